// Round 2
// baseline (15414.398 us; speedup 1.0000x reference)
//
#include <hip/hip_runtime.h>

#define TT 512
#define BB 1024
#define FF 32
#define HH 64
#define GG 256   // 4*H gates per direction

// Static device scratch — avoids any dependence on ws_size (suspected cause of
// the round-1 GPU memory fault: h1 needed 256MB+ of d_ws). Fully overwritten
// every call (layer0 writes all of g_h1, layer1 writes all of g_hf) so the
// harness's re-poison of d_ws/d_out cannot leak stale state through these.
__device__ float g_h1[(size_t)TT * BB * 2 * HH];   // [T][B][128], 256 MB
__device__ float g_hf[(size_t)BB * HH];            // [B][64] final fwd h of layer1

__device__ __forceinline__ float fsigm(float x) {
    float e = __builtin_amdgcn_exp2f(x * -1.44269504088896f);
    return __builtin_amdgcn_rcpf(1.0f + e);
}
__device__ __forceinline__ float ftanh(float x) {
    float e = __builtin_amdgcn_exp2f(x * -2.88539008177793f);
    return 2.0f * __builtin_amdgcn_rcpf(1.0f + e) - 1.0f;
}

// ---------------------------------------------------------------------------
// Layer 0 (both directions): fused input GEMM + recurrent scan.
// grid = 512 blocks: dir = blockIdx.x & 1, batch tile of 4 = blockIdx.x >> 1.
// 256 threads: thread tid owns gate row tid (weights in 96 VGPRs).
// ---------------------------------------------------------------------------
__global__ __launch_bounds__(256, 2) void lstm_layer0(
    const float* __restrict__ x,      // [B][T][F]
    const float* __restrict__ w_ih,   // [2][G][F]
    const float* __restrict__ w_hh,   // [2][G][H]
    const float* __restrict__ b_ih,   // [2][G]
    const float* __restrict__ b_hh)   // [2][G]
{
    const int tid  = threadIdx.x;
    const int dir  = blockIdx.x & 1;
    const int tile = blockIdx.x >> 1;
    const int b0   = tile * 4;

    __shared__ __align__(16) float x_lds[4][FF];
    __shared__ __align__(16) float h_lds[4][HH];
    __shared__ __align__(16) float gact[4][GG];

    float4 wi[8];   // w_ih[dir][gate][0:32]
    float4 wh[16];  // w_hh[dir][gate][0:64]
    {
        const float4* s0 = (const float4*)(w_ih + ((size_t)dir * GG + tid) * FF);
#pragma unroll
        for (int i = 0; i < 8; ++i) wi[i] = s0[i];
        const float4* s1 = (const float4*)(w_hh + ((size_t)dir * GG + tid) * HH);
#pragma unroll
        for (int i = 0; i < 16; ++i) wh[i] = s1[i];
    }
    const float bias = b_ih[dir * GG + tid] + b_hh[dir * GG + tid];

    h_lds[tid >> 6][tid & 63] = 0.0f;
    float c_reg = 0.0f;
    const int cb = tid >> 6;
    const int cj = tid & 63;
    const bool is_g = ((tid >> 6) == 2);   // gates 128..191 -> tanh (wave-uniform)

    for (int s = 0; s < TT; ++s) {
        const int t = (dir == 0) ? s : (TT - 1 - s);
        if (tid < 128) {
            int b = tid >> 5, f = tid & 31;
            x_lds[b][f] = x[((size_t)(b0 + b) * TT + t) * FF + f];
        }
        __syncthreads();   // x_lds + h_lds(prev step) ready

        float acc[4];
#pragma unroll
        for (int b = 0; b < 4; ++b) acc[b] = bias;
#pragma unroll
        for (int k = 0; k < 8; ++k) {
            float4 w4 = wi[k];
#pragma unroll
            for (int b = 0; b < 4; ++b) {
                float4 v = ((const float4*)x_lds[b])[k];   // wave-uniform broadcast
                acc[b] += w4.x * v.x; acc[b] += w4.y * v.y;
                acc[b] += w4.z * v.z; acc[b] += w4.w * v.w;
            }
        }
#pragma unroll
        for (int k = 0; k < 16; ++k) {
            float4 w4 = wh[k];
#pragma unroll
            for (int b = 0; b < 4; ++b) {
                float4 v = ((const float4*)h_lds[b])[k];   // wave-uniform broadcast
                acc[b] += w4.x * v.x; acc[b] += w4.y * v.y;
                acc[b] += w4.z * v.z; acc[b] += w4.w * v.w;
            }
        }
#pragma unroll
        for (int b = 0; b < 4; ++b)
            gact[b][tid] = is_g ? ftanh(acc[b]) : fsigm(acc[b]);
        __syncthreads();   // all gates ready (and all h_lds/x_lds reads done)

        {
            float ig = gact[cb][cj];
            float fg = gact[cb][HH + cj];
            float gg = gact[cb][2 * HH + cj];
            float og = gact[cb][3 * HH + cj];
            c_reg = fg * c_reg + ig * gg;
            float h = og * ftanh(c_reg);
            h_lds[cb][cj] = h;
            g_h1[((size_t)t * BB + (b0 + cb)) * (2 * HH) + dir * HH + cj] = h;
        }
        // next iteration's first __syncthreads orders h_lds write vs gate reads
    }
}

// ---------------------------------------------------------------------------
// Layer 1 forward scan. K = 128 (h1 row) + 64 (recurrent) = 192, split across
// 2 thread groups of 256 (96 weight VGPRs each), LDS reduction.
// grid = 256 blocks x 512 threads, batch tile of 4. Only final h is stored.
// ---------------------------------------------------------------------------
__global__ __launch_bounds__(512, 2) void lstm_layer1_fwd(
    const float* __restrict__ w_ih,   // [2][G][128]  (use dir 0)
    const float* __restrict__ w_hh,   // [2][G][64]
    const float* __restrict__ b_ih,
    const float* __restrict__ b_hh)
{
    const int tid  = threadIdx.x;
    const int grp  = tid >> 8;        // 0: k=0..95, 1: k=96..191
    const int gate = tid & 255;
    const int b0   = blockIdx.x * 4;

    __shared__ __align__(16) float x_lds[4][128];
    __shared__ __align__(16) float h_lds[4][HH];
    __shared__ __align__(16) float part[2][4][GG];
    __shared__ __align__(16) float gact[4][GG];

    float4 w[24];   // 96 floats of this thread's K-slice
    if (grp == 0) {
        const float4* s0 = (const float4*)(w_ih + (size_t)gate * 128);
#pragma unroll
        for (int i = 0; i < 24; ++i) w[i] = s0[i];
    } else {
        const float4* s0 = (const float4*)(w_ih + (size_t)gate * 128 + 96);
#pragma unroll
        for (int i = 0; i < 8; ++i) w[i] = s0[i];
        const float4* s1 = (const float4*)(w_hh + (size_t)gate * HH);
#pragma unroll
        for (int i = 0; i < 16; ++i) w[8 + i] = s1[i];
    }
    const float bias = (grp == 0) ? (b_ih[gate] + b_hh[gate]) : 0.0f;

    if (tid < 256) h_lds[tid >> 6][tid & 63] = 0.0f;
    float c_reg = 0.0f;
    const int cb = tid >> 6, cj = tid & 63;   // valid when tid < 256

    for (int t = 0; t < TT; ++t) {
        {
            int b = tid >> 7, col = tid & 127;
            x_lds[b][col] = g_h1[((size_t)t * BB + (b0 + b)) * 128 + col];
        }
        __syncthreads();   // x_lds + h_lds ready

        float acc[4];
#pragma unroll
        for (int b = 0; b < 4; ++b) acc[b] = bias;
        if (grp == 0) {
#pragma unroll
            for (int k = 0; k < 24; ++k) {
                float4 w4 = w[k];
#pragma unroll
                for (int b = 0; b < 4; ++b) {
                    float4 v = ((const float4*)x_lds[b])[k];
                    acc[b] += w4.x * v.x; acc[b] += w4.y * v.y;
                    acc[b] += w4.z * v.z; acc[b] += w4.w * v.w;
                }
            }
        } else {
#pragma unroll
            for (int k = 0; k < 8; ++k) {
                float4 w4 = w[k];
#pragma unroll
                for (int b = 0; b < 4; ++b) {
                    float4 v = ((const float4*)x_lds[b])[24 + k];   // cols 96..127
                    acc[b] += w4.x * v.x; acc[b] += w4.y * v.y;
                    acc[b] += w4.z * v.z; acc[b] += w4.w * v.w;
                }
            }
#pragma unroll
            for (int k = 0; k < 16; ++k) {
                float4 w4 = w[8 + k];
#pragma unroll
                for (int b = 0; b < 4; ++b) {
                    float4 v = ((const float4*)h_lds[b])[k];
                    acc[b] += w4.x * v.x; acc[b] += w4.y * v.y;
                    acc[b] += w4.z * v.z; acc[b] += w4.w * v.w;
                }
            }
        }
#pragma unroll
        for (int b = 0; b < 4; ++b) part[grp][b][gate] = acc[b];
        __syncthreads();   // partials ready (x_lds reads done)

        {
            const bool is_g = (gate >= 128) && (gate < 192);   // wave-uniform
#pragma unroll
            for (int bb = 0; bb < 2; ++bb) {
                int b = grp * 2 + bb;
                float sgt = part[0][b][gate] + part[1][b][gate];
                gact[b][gate] = is_g ? ftanh(sgt) : fsigm(sgt);
            }
        }
        __syncthreads();   // gact ready

        if (tid < 256) {
            float ig = gact[cb][cj];
            float fg = gact[cb][HH + cj];
            float gg = gact[cb][2 * HH + cj];
            float og = gact[cb][3 * HH + cj];
            c_reg = fg * c_reg + ig * gg;
            float h = og * ftanh(c_reg);
            h_lds[cb][cj] = h;
            if (t == TT - 1) g_hf[(size_t)(b0 + cb) * HH + cj] = h;
        }
        // next iteration's first __syncthreads orders h_lds write vs reads
    }
}

// ---------------------------------------------------------------------------
// Layer 1 backward single step (zero state on h1[T-1]) + FC head.
// grid = 256 blocks x 256 threads, batch tile of 4.
// ---------------------------------------------------------------------------
__global__ __launch_bounds__(256, 2) void lstm_final(
    const float* __restrict__ w_ih,   // [2][G][128] (use dir 1)
    const float* __restrict__ b_ih,
    const float* __restrict__ b_hh,
    const float* __restrict__ fc_w,   // [2][128]
    const float* __restrict__ fc_b,   // [2]
    float* __restrict__ out)          // [B][2]
{
    const int tid = threadIdx.x;
    const int b0  = blockIdx.x * 4;

    __shared__ __align__(16) float x_lds[4][128];
    __shared__ __align__(16) float gact[4][GG];
    __shared__ __align__(16) float last[4][128];

#pragma unroll
    for (int r = 0; r < 2; ++r) {
        int idx = tid + r * 256;
        int b = idx >> 7, col = idx & 127;
        x_lds[b][col] = g_h1[((size_t)(TT - 1) * BB + (b0 + b)) * 128 + col];
    }

    float4 w[32];   // w_ih1[1][gate][0:128]
    {
        const float4* s0 = (const float4*)(w_ih + ((size_t)GG + tid) * 128);
#pragma unroll
        for (int i = 0; i < 32; ++i) w[i] = s0[i];
    }
    const float bias = b_ih[GG + tid] + b_hh[GG + tid];
    __syncthreads();

    float acc[4];
#pragma unroll
    for (int b = 0; b < 4; ++b) acc[b] = bias;
#pragma unroll
    for (int k = 0; k < 32; ++k) {
        float4 w4 = w[k];
#pragma unroll
        for (int b = 0; b < 4; ++b) {
            float4 v = ((const float4*)x_lds[b])[k];
            acc[b] += w4.x * v.x; acc[b] += w4.y * v.y;
            acc[b] += w4.z * v.z; acc[b] += w4.w * v.w;
        }
    }
    const bool is_g = ((tid >> 6) == 2);
#pragma unroll
    for (int b = 0; b < 4; ++b)
        gact[b][tid] = is_g ? ftanh(acc[b]) : fsigm(acc[b]);
    __syncthreads();

    {
        const int cb = tid >> 6, cj = tid & 63;
        float ig = gact[cb][cj];
        float gg = gact[cb][2 * HH + cj];
        float og = gact[cb][3 * HH + cj];
        float c = ig * gg;
        float h = og * ftanh(c);
        last[cb][HH + cj] = h;
        last[cb][cj] = g_hf[(size_t)(b0 + cb) * HH + cj];
    }
    __syncthreads();

    if (tid < 8) {
        int b = tid >> 1, o = tid & 1;
        float a = fc_b[o];
#pragma unroll
        for (int j = 0; j < 128; ++j) a += fc_w[o * 128 + j] * last[b][j];
        out[(size_t)(b0 + b) * 2 + o] = a;
    }
}

extern "C" void kernel_launch(void* const* d_in, const int* in_sizes, int n_in,
                              void* d_out, int out_size, void* d_ws, size_t ws_size,
                              hipStream_t stream) {
    const float* x     = (const float*)d_in[0];
    const float* w_ih0 = (const float*)d_in[1];
    const float* w_hh0 = (const float*)d_in[2];
    const float* b_ih0 = (const float*)d_in[3];
    const float* b_hh0 = (const float*)d_in[4];
    const float* w_ih1 = (const float*)d_in[5];
    const float* w_hh1 = (const float*)d_in[6];
    const float* b_ih1 = (const float*)d_in[7];
    const float* b_hh1 = (const float*)d_in[8];
    const float* fc_w  = (const float*)d_in[9];
    const float* fc_b  = (const float*)d_in[10];
    float* out = (float*)d_out;

    lstm_layer0<<<512, 256, 0, stream>>>(x, w_ih0, w_hh0, b_ih0, b_hh0);
    lstm_layer1_fwd<<<256, 512, 0, stream>>>(w_ih1, w_hh1, b_ih1, b_hh1);
    lstm_final<<<256, 256, 0, stream>>>(w_ih1, b_ih1, b_hh1, fc_w, fc_b, out);
}